// Round 1
// 1048.888 us; speedup vs baseline: 1.0164x; 1.0164x over previous
//
#include <hip/hip_runtime.h>
#include <hip/hip_fp16.h>

typedef float f32x2 __attribute__((ext_vector_type(2)));

#define TSEQ 512
#define IND 64
#define HID 10
#define NG 40
#define BATCH 4096
#define ROWS (BATCH * TSEQ)
#define RPB 256          // rows per block in phase 1
#define LSTRIDE 21       // padded LDS row stride in dwords (20 data + 1)
#define CSTR 68          // input-staging LDS row stride in dwords (64 + 4 pad, keeps 16B align)

#define L2E   1.4426950408889634f
#define L2E2  2.8853900817779268f

__device__ __forceinline__ float lane_f(float v, int l) {
  return __builtin_bit_cast(float, __builtin_amdgcn_readlane(__builtin_bit_cast(int, v), l));
}

// Phase 1: xg[row][g] = fp16( (x[row]·W_ih[g] + b_ih[g] + b_hh[g]) * scale_g )
// scale_g = -log2e for i,f,o gates; -2*log2e for g gate (folds the exp2 args).
// x rows are staged through LDS in 64-row chunks so global loads are fully
// coalesced (1 KB/instr) instead of lane-stride-256B (64 line-splits/instr).
// Results staged in LDS, written out fully coalesced as dwordx4.
__global__ __launch_bounds__(256) void input_proj(
    const float* __restrict__ x, const float* __restrict__ W_ih,
    const float* __restrict__ b_ih, const float* __restrict__ b_hh,
    unsigned int* __restrict__ xg)           // packed half2, ROWS*20 dwords
{
  __shared__ __align__(16) unsigned int st[RPB * LSTRIDE];   // 21504 B
  float* const fin = (float*)st;                             // reused: 64*CSTR*4 = 17408 B
  const int tid = threadIdx.x;
  const int lr  = tid & 63;                  // row-within-chunk
  const int myc = tid >> 6;                  // which chunk holds my row (== wave id)
  const long long rowbase = (long long)blockIdx.x * RPB;

  f32x2 xr[32];
#pragma unroll 1
  for (int c = 0; c < 4; ++c) {
    // cooperative coalesced load of rows [rowbase + 64c, +64): 1024 float4s
    const float4* src = (const float4*)(x + (rowbase + (long long)c * 64) * IND);
#pragma unroll
    for (int p = 0; p < 4; ++p) {
      int j = tid + 256 * p;                 // float4 index within the 16 KB chunk
      float4 v = src[j];
      int r = j >> 4, m = (j & 15) << 2;     // row, dword-col
      *(float4*)&fin[r * CSTR + m] = v;
    }
    __syncthreads();
    if (myc == c) {
#pragma unroll
      for (int i = 0; i < 16; ++i) {
        float4 v = *(const float4*)&fin[lr * CSTR + 4 * i];
        xr[2*i]   = f32x2{v.x, v.y};
        xr[2*i+1] = f32x2{v.z, v.w};
      }
    }
    __syncthreads();                         // buffer reused by next chunk / output staging
  }

#pragma unroll 1
  for (int gc = 0; gc < 10; ++gc) {          // 4 gates per iteration
    const f32x2* w0 = (const f32x2*)(W_ih + (4*gc + 0) * IND);  // wave-uniform
    const f32x2* w1 = (const f32x2*)(W_ih + (4*gc + 1) * IND);
    const f32x2* w2 = (const f32x2*)(W_ih + (4*gc + 2) * IND);
    const f32x2* w3 = (const f32x2*)(W_ih + (4*gc + 3) * IND);
    f32x2 a0 = {0.f, 0.f}, a1 = {0.f, 0.f}, a2 = {0.f, 0.f}, a3 = {0.f, 0.f};
#pragma unroll
    for (int k = 0; k < 32; ++k) {
      a0 = __builtin_elementwise_fma(xr[k], w0[k], a0);
      a1 = __builtin_elementwise_fma(xr[k], w1[k], a1);
      a2 = __builtin_elementwise_fma(xr[k], w2[k], a2);
      a3 = __builtin_elementwise_fma(xr[k], w3[k], a3);
    }
    float s0 = ((4*gc + 0) / 10 == 2) ? -L2E2 : -L2E;
    float s1 = ((4*gc + 1) / 10 == 2) ? -L2E2 : -L2E;
    float s2 = ((4*gc + 2) / 10 == 2) ? -L2E2 : -L2E;
    float s3 = ((4*gc + 3) / 10 == 2) ? -L2E2 : -L2E;
    float g0 = (a0.x + a0.y + b_ih[4*gc + 0] + b_hh[4*gc + 0]) * s0;
    float g1 = (a1.x + a1.y + b_ih[4*gc + 1] + b_hh[4*gc + 1]) * s1;
    float g2 = (a2.x + a2.y + b_ih[4*gc + 2] + b_hh[4*gc + 2]) * s2;
    float g3 = (a3.x + a3.y + b_ih[4*gc + 3] + b_hh[4*gc + 3]) * s3;
    _Float16 q0 = (_Float16)g0, q1 = (_Float16)g1, q2 = (_Float16)g2, q3 = (_Float16)g3;
    unsigned p01 = (unsigned)__builtin_bit_cast(unsigned short, q0) |
                   ((unsigned)__builtin_bit_cast(unsigned short, q1) << 16);
    unsigned p23 = (unsigned)__builtin_bit_cast(unsigned short, q2) |
                   ((unsigned)__builtin_bit_cast(unsigned short, q3) << 16);
    st[tid * LSTRIDE + 2*gc]     = p01;
    st[tid * LSTRIDE + 2*gc + 1] = p23;
  }
  __syncthreads();

  // Coalesced copy-out: 256 rows x 20 dwords = 5120 dwords per block.
  const long long obase = (long long)blockIdx.x * (RPB * 20);
#pragma unroll
  for (int it = 0; it < 5; ++it) {
    int d0 = it * 1024 + tid * 4;            // d0 % 4 == 0 -> never crosses a 20-dword row
    int r = d0 / 20, m = d0 % 20;
    const unsigned* p = &st[r * LSTRIDE + m];
    uint4 vv; vv.x = p[0]; vv.y = p[1]; vv.z = p[2]; vv.w = p[3];
    *(uint4*)(xg + obase + d0) = vv;
  }
}

// Phase 2: serial recurrence. One wave per batch element; lane = gate.
__global__ __launch_bounds__(64) void lstm_rec(
    const _Float16* __restrict__ xg, const float* __restrict__ W_hh,
    float* __restrict__ out_seq, float* __restrict__ out_h)
{
  __shared__ float hbuf[80];
  const int b    = blockIdx.x;
  const int lane = threadIdx.x;
  const int g    = lane < NG ? lane : NG - 1;
  const int li   = lane < NG ? lane : 0;
  const int tt   = g / HID;

  const float aMul = (tt == 2) ? 2.0f : 1.0f;
  const float aAdd = (tt == 2) ? -1.0f : 0.0f;
  const float mscale = (tt == 2) ? -L2E2 : -L2E;

  float whh[HID];
#pragma unroll
  for (int u = 0; u < HID; ++u) whh[u] = W_hh[g * HID + u] * mscale;

  const _Float16* xr = xg + (size_t)b * TSEQ * NG + li;
  float* orow = out_seq + (size_t)b * TSEQ * HID;

  float h = 0.0f, c = 0.0f;
  _Float16 xb[8];
#pragma unroll
  for (int j = 0; j < 8; ++j) xb[j] = xr[j * NG];      // 8-deep prefetch

  for (int t0 = 0; t0 < TSEQ; t0 += 8) {
#pragma unroll
    for (int j = 0; j < 8; ++j) {
      float acc = (float)xb[j];                        // pre-scaled by mscale
      if (t0 + 8 < TSEQ) xb[j] = xr[(t0 + j + 8) * NG];

#pragma unroll
      for (int u = 0; u < HID; ++u)
        acc = fmaf(lane_f(h, u), whh[u], acc);

      float e   = __builtin_amdgcn_exp2f(acc);
      float s   = __builtin_amdgcn_rcpf(1.0f + e);
      float act = fmaf(aMul, s, aAdd);                 // sigmoid (i,f,o) / tanh (g)

      float iv = __shfl(act, lane);
      float fv = __shfl(act, lane + 10);
      float gv = __shfl(act, lane + 20);
      float ov = __shfl(act, lane + 30);

      c = fmaf(fv, c, iv * gv);
      float e2 = __builtin_amdgcn_exp2f(-L2E2 * c);
      float th = fmaf(2.0f, __builtin_amdgcn_rcpf(1.0f + e2), -1.0f);
      h = ov * th;

      if (lane < HID) hbuf[j * HID + lane] = h;
    }
    __syncthreads();                                   // single wave: cheap fence
    if (lane < 40) {
      float2 p; p.x = hbuf[2 * lane]; p.y = hbuf[2 * lane + 1];
      ((float2*)(orow + t0 * HID))[lane] = p;          // 320 B contiguous store
    }
    __syncthreads();
  }
  if (lane < HID) out_h[(size_t)b * HID + lane] = h;
}

extern "C" void kernel_launch(void* const* d_in, const int* in_sizes, int n_in,
                              void* d_out, int out_size, void* d_ws, size_t ws_size,
                              hipStream_t stream) {
  const float* x    = (const float*)d_in[0];
  const float* W_ih = (const float*)d_in[1];
  const float* W_hh = (const float*)d_in[2];
  const float* b_ih = (const float*)d_in[3];
  const float* b_hh = (const float*)d_in[4];

  unsigned int* xg = (unsigned int*)d_ws;                       // ROWS*20 dwords (168 MB)
  float* out_seq = (float*)d_out;                               // [B, T, H]
  float* out_h   = (float*)d_out + (size_t)BATCH * TSEQ * HID;  // [B, H]

  input_proj<<<dim3(ROWS / RPB), dim3(RPB), 0, stream>>>(x, W_ih, b_ih, b_hh, xg);
  lstm_rec<<<dim3(BATCH), dim3(64), 0, stream>>>((const _Float16*)xg, W_hh, out_seq, out_h);
}

// Round 2
// 929.761 us; speedup vs baseline: 1.1466x; 1.1281x over previous
//
#include <hip/hip_runtime.h>
#include <hip/hip_fp16.h>

typedef float f32x2 __attribute__((ext_vector_type(2)));

#define TSEQ 512
#define IND 64
#define HID 10
#define NG 40
#define BATCH 4096
#define ROWS (BATCH * TSEQ)
#define RPB 256          // rows per block in phase 1
#define LSTRIDE 21       // padded LDS row stride in dwords (20 data + 1)
#define CSTR 68          // input-staging LDS row stride in dwords (64 + 4 pad, keeps 16B align)

#define L2E   1.4426950408889634f
#define L2E2  2.8853900817779268f

static __device__ __forceinline__ float h2f_lo(unsigned v) {
  return (float)__builtin_bit_cast(_Float16, (unsigned short)(v & 0xffffu));
}
static __device__ __forceinline__ float h2f_hi(unsigned v) {
  return (float)__builtin_bit_cast(_Float16, (unsigned short)(v >> 16));
}

// Phase 1: per row, compute all 40 gate pre-activations, scale by -log2e
// (i,f,o) or -2*log2e (g), quantize to fp16, and store REGROUPED PER UNIT:
// dword pair u = [ half(i_u) | half(f_u)<<16 ,  half(g_u) | half(o_u)<<16 ].
// W_ih is staged in LDS (10 KB) so the inner loop reads broadcast ds_read
// instead of 1280 per-lane global loads with exposed L1 latency.
__global__ __launch_bounds__(256) void input_proj(
    const float* __restrict__ x, const float* __restrict__ W_ih,
    const float* __restrict__ b_ih, const float* __restrict__ b_hh,
    unsigned int* __restrict__ xg)           // ROWS*20 dwords
{
  __shared__ __align__(16) unsigned int st[RPB * LSTRIDE];   // 21504 B (x-stage, then out-stage)
  __shared__ __align__(16) float wlds[NG * IND];             // 10240 B
  float* const fin = (float*)st;
  const int tid = threadIdx.x;
  const int lr  = tid & 63;
  const int myc = tid >> 6;
  const long long rowbase = (long long)blockIdx.x * RPB;

  // W_ih -> LDS (visible after the first __syncthreads below)
  for (int i = tid; i < NG * IND; i += 256) wlds[i] = W_ih[i];

  f32x2 xr[32];
#pragma unroll 1
  for (int c = 0; c < 4; ++c) {
    const float4* src = (const float4*)(x + (rowbase + (long long)c * 64) * IND);
#pragma unroll
    for (int p = 0; p < 4; ++p) {
      int j = tid + 256 * p;
      float4 v = src[j];
      int r = j >> 4, m = (j & 15) << 2;
      *(float4*)&fin[r * CSTR + m] = v;
    }
    __syncthreads();
    if (myc == c) {
#pragma unroll
      for (int i = 0; i < 16; ++i) {
        float4 v = *(const float4*)&fin[lr * CSTR + 4 * i];
        xr[2*i]   = f32x2{v.x, v.y};
        xr[2*i+1] = f32x2{v.z, v.w};
      }
    }
    __syncthreads();
  }

#pragma unroll 1
  for (int u = 0; u < HID; ++u) {            // 4 gates (i,f,g,o) of unit u
    const f32x2* w0 = (const f32x2*)&wlds[(u     ) * IND];
    const f32x2* w1 = (const f32x2*)&wlds[(u + 10) * IND];
    const f32x2* w2 = (const f32x2*)&wlds[(u + 20) * IND];
    const f32x2* w3 = (const f32x2*)&wlds[(u + 30) * IND];
    f32x2 a0 = {0.f, 0.f}, a1 = {0.f, 0.f}, a2 = {0.f, 0.f}, a3 = {0.f, 0.f};
#pragma unroll
    for (int k = 0; k < 32; ++k) {
      a0 = __builtin_elementwise_fma(xr[k], w0[k], a0);
      a1 = __builtin_elementwise_fma(xr[k], w1[k], a1);
      a2 = __builtin_elementwise_fma(xr[k], w2[k], a2);
      a3 = __builtin_elementwise_fma(xr[k], w3[k], a3);
    }
    float g0 = (a0.x + a0.y + b_ih[u     ] + b_hh[u     ]) * (-L2E);
    float g1 = (a1.x + a1.y + b_ih[u + 10] + b_hh[u + 10]) * (-L2E);
    float g2 = (a2.x + a2.y + b_ih[u + 20] + b_hh[u + 20]) * (-L2E2);
    float g3 = (a3.x + a3.y + b_ih[u + 30] + b_hh[u + 30]) * (-L2E);
    _Float16 q0 = (_Float16)g0, q1 = (_Float16)g1, q2 = (_Float16)g2, q3 = (_Float16)g3;
    unsigned p01 = (unsigned)__builtin_bit_cast(unsigned short, q0) |
                   ((unsigned)__builtin_bit_cast(unsigned short, q1) << 16);
    unsigned p23 = (unsigned)__builtin_bit_cast(unsigned short, q2) |
                   ((unsigned)__builtin_bit_cast(unsigned short, q3) << 16);
    st[tid * LSTRIDE + 2*u]     = p01;
    st[tid * LSTRIDE + 2*u + 1] = p23;
  }
  __syncthreads();

  const long long obase = (long long)blockIdx.x * (RPB * 20);
#pragma unroll
  for (int it = 0; it < 5; ++it) {
    int d0 = it * 1024 + tid * 4;
    int r = d0 / 20, m = d0 % 20;
    const unsigned* p = &st[r * LSTRIDE + m];
    uint4 vv; vv.x = p[0]; vv.y = p[1]; vv.z = p[2]; vv.w = p[3];
    *(uint4*)(xg + obase + d0) = vv;
  }
}

// Phase 2: lane = (batch-in-wave, hidden-unit). Each lane computes all 4
// gates for its unit -> c/h update is lane-local (no shuffles). h broadcast
// via a rolling LDS buffer. Single wave per block -> no barriers, so the
// 8-deep global prefetch is never drained by a waitcnt vmcnt(0).
__global__ __launch_bounds__(64) void lstm_rec(
    const uint2* __restrict__ xg, const float* __restrict__ W_hh,
    float* __restrict__ out_seq, float* __restrict__ out_h)
{
  __shared__ __align__(16) float hb[8][4][16];   // rolling h: [t&7][batch][unit]
  const int lane = threadIdx.x;
  const int bi = lane >> 4;
  const int u  = lane & 15;
  const int uc = (u < HID) ? u : HID - 1;
  const size_t b = (size_t)blockIdx.x * 4 + bi;

  // pre-scaled recurrent weights: rows u (i), u+10 (f), u+20 (g), u+30 (o)
  float wi[HID], wf[HID], wg[HID], wo[HID];
#pragma unroll
  for (int k = 0; k < HID; ++k) {
    wi[k] = W_hh[(uc     ) * HID + k] * (-L2E);
    wf[k] = W_hh[(uc + 10) * HID + k] * (-L2E);
    wg[k] = W_hh[(uc + 20) * HID + k] * (-L2E2);
    wo[k] = W_hh[(uc + 30) * HID + k] * (-L2E);
  }

  const uint2* xp = xg + b * TSEQ * HID + uc;
  float h = 0.f, c = 0.f;
  hb[7][bi][u] = 0.f;                            // h_{-1} = 0

  uint2 xb[8];
#pragma unroll
  for (int j = 0; j < 8; ++j) xb[j] = xp[(size_t)j * HID];

  for (int t0 = 0; t0 < TSEQ; t0 += 8) {
#pragma unroll
    for (int j = 0; j < 8; ++j) {
      uint2 xv = xb[j];
      if (t0 + 8 < TSEQ) xb[j] = xp[(size_t)(t0 + j + 8) * HID];
      float ai = h2f_lo(xv.x);                   // i (pre-scaled by -log2e)
      float af = h2f_hi(xv.x);                   // f
      float ag = h2f_lo(xv.y);                   // g (pre-scaled by -2log2e)
      float ao = h2f_hi(xv.y);                   // o

      const float* hr = &hb[(j + 7) & 7][bi][0];
      float4 h03 = *(const float4*)hr;
      float4 h47 = *(const float4*)(hr + 4);
      float2 h89 = *(const float2*)(hr + 8);
      float hhv[HID] = {h03.x, h03.y, h03.z, h03.w,
                        h47.x, h47.y, h47.z, h47.w, h89.x, h89.y};
#pragma unroll
      for (int k = 0; k < HID; ++k) {
        ai = fmaf(hhv[k], wi[k], ai);
        af = fmaf(hhv[k], wf[k], af);
        ag = fmaf(hhv[k], wg[k], ag);
        ao = fmaf(hhv[k], wo[k], ao);
      }
      float i_ = __builtin_amdgcn_rcpf(1.f + __builtin_amdgcn_exp2f(ai));
      float f_ = __builtin_amdgcn_rcpf(1.f + __builtin_amdgcn_exp2f(af));
      float g_ = fmaf(2.f, __builtin_amdgcn_rcpf(1.f + __builtin_amdgcn_exp2f(ag)), -1.f);
      float o_ = __builtin_amdgcn_rcpf(1.f + __builtin_amdgcn_exp2f(ao));

      c = fmaf(f_, c, i_ * g_);
      float th = fmaf(2.f, __builtin_amdgcn_rcpf(1.f + __builtin_amdgcn_exp2f(-L2E2 * c)), -1.f);
      h = o_ * th;
      hb[j][bi][u] = h;
    }
    // coalesced dump of 8 timesteps x 4 batches x 10 units
#pragma unroll
    for (int k = 0; k < 5; ++k) {
      int e = lane + 64 * k;                     // 0..319
      int bb = e / 80, rem = e - bb * 80;        // rem = jj*10+uu
      int jj = rem / 10, uu = rem - jj * 10;
      out_seq[((size_t)(blockIdx.x * 4 + bb) * TSEQ + t0) * HID + rem] = hb[jj][bb][uu];
    }
  }
  if (u < HID) out_h[b * HID + u] = h;
}

extern "C" void kernel_launch(void* const* d_in, const int* in_sizes, int n_in,
                              void* d_out, int out_size, void* d_ws, size_t ws_size,
                              hipStream_t stream) {
  const float* x    = (const float*)d_in[0];
  const float* W_ih = (const float*)d_in[1];
  const float* W_hh = (const float*)d_in[2];
  const float* b_ih = (const float*)d_in[3];
  const float* b_hh = (const float*)d_in[4];

  unsigned int* xg = (unsigned int*)d_ws;                       // ROWS*20 dwords (168 MB)
  float* out_seq = (float*)d_out;                               // [B, T, H]
  float* out_h   = (float*)d_out + (size_t)BATCH * TSEQ * HID;  // [B, H]

  input_proj<<<dim3(ROWS / RPB), dim3(RPB), 0, stream>>>(x, W_ih, b_ih, b_hh, xg);
  lstm_rec<<<dim3(BATCH / 4), dim3(64), 0, stream>>>((const uint2*)xg, W_hh, out_seq, out_h);
}